// Round 18
// baseline (189.495 us; speedup 1.0000x reference)
//
#include <hip/hip_runtime.h>
#include <hip/hip_bf16.h>

using bf16 = __hip_bfloat16;
typedef __attribute__((ext_vector_type(8))) __bf16 bf16x8;
typedef __attribute__((ext_vector_type(4))) short s16x4;
typedef __attribute__((ext_vector_type(4))) float f32x4;

#define B_   4
#define T_   2048
#define D_   1024
#define H_   16
#define HD_  64
#define BH_  (B_ * H_)
#define BT_  (B_ * T_)

// Q pre-scale: 1/sqrt(64) * log2(e)  -> softmax computed with exp2
#define QSCALE 0.18033688011112042f

__device__ __forceinline__ void gld_lds16(const void* g, void* l) {
    __builtin_amdgcn_global_load_lds(
        (const __attribute__((address_space(1))) unsigned int*)g,
        (__attribute__((address_space(3))) unsigned int*)l,
        16, 0, 0);
}

__device__ __forceinline__ f32x4 mfma16(s16x4 a, s16x4 b, f32x4 c) {
#if defined(__HIP_DEVICE_COMPILE__)
  #if __has_builtin(__builtin_amdgcn_mfma_f32_16x16x16bf16_1k)
    return __builtin_amdgcn_mfma_f32_16x16x16bf16_1k(a, b, c, 0, 0, 0);
  #else
    f32x4 d;
    asm volatile("v_mfma_f32_16x16x16_bf16 %0, %1, %2, %3\n\ts_nop 7\n\ts_nop 7"
                 : "=v"(d) : "v"(a), "v"(b), "v"(c));
    return d;
  #endif
#else
    (void)a; (void)b;
    return c;
#endif
}

__device__ __forceinline__ unsigned bfbits(float x) {
    return (unsigned)__builtin_bit_cast(unsigned short, __float2bfloat16(x));
}

// ---------------------------------------------------------------- fused prep
__global__ __launch_bounds__(256)
void prep_kernel(const float* __restrict__ x,
                 const float* __restrict__ W_attn,
                 const float* __restrict__ W_proj,
                 bf16* __restrict__ xh, bf16* __restrict__ WaT, bf16* __restrict__ WpT) {
    __shared__ float tile[32][33];
    const int blk = blockIdx.x;
    const int tid = threadIdx.x;

    if (blk < 4096) {                       // cast x (8 elems/thread, 16B stores)
        const size_t i = ((size_t)blk * 256 + tid) * 8;
        float4 v0 = *reinterpret_cast<const float4*>(x + i);
        float4 v1 = *reinterpret_cast<const float4*>(x + i + 4);
        uint4 p;
        p.x = bfbits(v0.x) | (bfbits(v0.y) << 16);
        p.y = bfbits(v0.z) | (bfbits(v0.w) << 16);
        p.z = bfbits(v1.x) | (bfbits(v1.y) << 16);
        p.w = bfbits(v1.z) | (bfbits(v1.w) << 16);
        *reinterpret_cast<uint4*>(xh + i) = p;
        return;
    }

    if (blk < 4096 + 3072) {                // W_attn [1024][3072] -> WaT [3072][1024]
        const int t = blk - 4096;
        const int nb = (t % 96) * 32, kb = (t / 96) * 32;
        const int tx = tid & 31, ty = tid >> 5;
        #pragma unroll
        for (int i = 0; i < 32; i += 8)
            tile[ty + i][tx] = W_attn[(size_t)(kb + ty + i) * 3072 + nb + tx];
        __syncthreads();
        #pragma unroll
        for (int i = 0; i < 32; i += 8)
            WaT[(size_t)(nb + ty + i) * 1024 + kb + tx] = __float2bfloat16(tile[tx][ty + i]);
    } else {                                // W_proj [1024][1024] -> WpT
        const int t = blk - 4096 - 3072;
        const int nb = (t % 32) * 32, kb = (t / 32) * 32;
        const int tx = tid & 31, ty = tid >> 5;
        #pragma unroll
        for (int i = 0; i < 32; i += 8)
            tile[ty + i][tx] = W_proj[(size_t)(kb + ty + i) * 1024 + nb + tx];
        __syncthreads();
        #pragma unroll
        for (int i = 0; i < 32; i += 8)
            WpT[(size_t)(nb + ty + i) * 1024 + kb + tx] = __float2bfloat16(tile[tx][ty + i]);
    }
}

// ---------------------------------------------------------------- QKV GEMM: 256x256, 8-phase
// K=1024 = 16 K-tiles of 64. 512 thr / 8 waves (2Mx4N), per-wave C 128x64 (acc[8][4]).
// LDS 128KB: 2 bufs x {A 32KB, B 32KB}; rows of 128B, chunk ^= row&7 swizzle (2-way=free).
// Per iter (2 K-tiles): 8 phases of {ds_read(4 A +8 B at tile start) | 2 DMA stage |
// bar | lgkmcnt0 | setprio1 16xMFMA setprio0 | vmcnt(N) | bar}. Stage tiles t+2/t+3,
// targets freed >=1 barrier earlier (audited). Per-phase-end vmcnt derived from the
// 16-call/iter issue ledger: steady [10,10,12,8,10,10,12,8]; tail [10,8,8,2,2,0,0,-].
__global__ __launch_bounds__(512, 2)
void gemm_qkv8p(const bf16* __restrict__ Ap, const bf16* __restrict__ Bp,
                const float* __restrict__ bias,
                bf16* __restrict__ Qo, bf16* __restrict__ Ko, bf16* __restrict__ Vo) {
    extern __shared__ char smem[];
    const int bn = blockIdx.x * 256;         // x = n (12): consecutive blocks share A-panel
    const int bm = blockIdx.y * 256;
    const int tid  = threadIdx.x;
    const int wid  = tid >> 6;
    const int lane = tid & 63;
    const int wr = (wid >> 2) * 128;
    const int wc = (wid & 3) * 64;
    const int ln_g = lane >> 4;
    const int ln_c = lane & 15;

    f32x4 acc[8][4] = {};
    bf16x8 brg[4][2];

    // staging: call J = 64 rows; lane l -> row wid*8 + (l>>3), lds chunk l&7,
    // global chunk (l&7)^((l>>3)&7)  (inverse swizzle on source)
    const int srw = wid * 8 + (lane >> 3);
    const int gck = ((lane & 7) ^ ((lane >> 3) & 7)) * 8;   // elem offset
    const int wlo = wid * 1024;

    // read-side swizzled chunk offsets (bytes): G=ln_g (ks=0), G=4+ln_g (ks=1)
    const int c0 = ((ln_g)     ^ (ln_c & 7)) * 16;
    const int c1 = ((4 + ln_g) ^ (ln_c & 7)) * 16;

#define GA(T_, J_, BO_) gld_lds16(Ap + (size_t)(bm + (J_) * 64 + srw) * 1024 + (T_) * 64 + gck, \
                                  smem + (BO_) + (J_) * 8192 + wlo)
#define GB(T_, J_, BO_) gld_lds16(Bp + (size_t)(bn + (J_) * 64 + srw) * 1024 + (T_) * 64 + gck, \
                                  smem + (BO_) + 32768 + (J_) * 8192 + wlo)
#define SB01(T_, BO_) { GB(T_, 0, BO_); GB(T_, 1, BO_); }
#define SB23(T_, BO_) { GB(T_, 2, BO_); GB(T_, 3, BO_); }
#define SA02(T_, BO_) { GA(T_, 0, BO_); GA(T_, 2, BO_); }
#define SA13(T_, BO_) { GA(T_, 1, BO_); GA(T_, 3, BO_); }
#define NOSTG {}

#define PH(BO_, Q0_, RB_, STG_, VM_) {                                                    \
    const char* aB_ = smem + (BO_) + (wr + ln_c) * 128;                                   \
    const char* bB_ = smem + (BO_) + 32768 + (wc + ln_c) * 128;                           \
    bf16x8 a_[2][2];                                                                      \
    _Pragma("unroll")                                                                     \
    for (int dm = 0; dm < 2; ++dm) {                                                      \
        a_[dm][0] = *(const bf16x8*)(aB_ + ((Q0_) * 2 + dm) * 2048 + c0);                 \
        a_[dm][1] = *(const bf16x8*)(aB_ + ((Q0_) * 2 + dm) * 2048 + c1);                 \
    }                                                                                     \
    if (RB_) {                                                                            \
        _Pragma("unroll")                                                                 \
        for (int n = 0; n < 4; ++n) {                                                     \
            brg[n][0] = *(const bf16x8*)(bB_ + n * 2048 + c0);                            \
            brg[n][1] = *(const bf16x8*)(bB_ + n * 2048 + c1);                            \
        }                                                                                 \
    }                                                                                     \
    STG_;                                                                                 \
    __builtin_amdgcn_s_barrier();                                                         \
    asm volatile("s_waitcnt lgkmcnt(0)" ::: "memory");                                    \
    __builtin_amdgcn_sched_barrier(0);                                                    \
    __builtin_amdgcn_s_setprio(1);                                                        \
    _Pragma("unroll")                                                                     \
    for (int dm = 0; dm < 2; ++dm)                                                        \
        _Pragma("unroll")                                                                 \
        for (int n = 0; n < 4; ++n) {                                                     \
            acc[(Q0_) * 2 + dm][n] = __builtin_amdgcn_mfma_f32_16x16x32_bf16(             \
                a_[dm][0], brg[n][0], acc[(Q0_) * 2 + dm][n], 0, 0, 0);                   \
            acc[(Q0_) * 2 + dm][n] = __builtin_amdgcn_mfma_f32_16x16x32_bf16(             \
                a_[dm][1], brg[n][1], acc[(Q0_) * 2 + dm][n], 0, 0, 0);                   \
        }                                                                                 \
    __builtin_amdgcn_s_setprio(0);                                                        \
    __builtin_amdgcn_sched_barrier(0);                                                    \
    asm volatile("s_waitcnt vmcnt(" #VM_ ")" ::: "memory");                               \
    __builtin_amdgcn_s_barrier();                                                         \
}

    // prologue: tiles 0 (buf0) and 1 (buf1), exactly in ledger order (#1..#16)
    SB01(0, 0); SB23(0, 0); SA02(0, 0); SA13(0, 0);
    SB01(1, 65536); SB23(1, 65536); SA02(1, 65536); SA13(1, 65536);
    asm volatile("s_waitcnt vmcnt(10)" ::: "memory");   // #1-#6 landed (B0 all + A0{0,2})
    __builtin_amdgcn_s_barrier();
    __builtin_amdgcn_sched_barrier(0);

    #pragma unroll 1
    for (int i = 0; i < 7; ++i) {
        const int t0 = 2 * i;
        PH(0,     0, 1, { if (i) SA13(t0 + 1, 65536); }, 10)
        PH(0,     1, 0, SB01(t0 + 2, 0),      10)
        PH(0,     2, 0, SB23(t0 + 2, 0),      12)
        PH(0,     3, 0, SA02(t0 + 2, 0),      8)
        PH(65536, 0, 1, SA13(t0 + 2, 0),      10)
        PH(65536, 1, 0, SB01(t0 + 3, 65536),  10)
        PH(65536, 2, 0, SB23(t0 + 3, 65536),  12)
        PH(65536, 3, 0, SA02(t0 + 3, 65536),  8)
    }
    // tail iter: tiles 14 (buf0), 15 (buf1); only ph1 stages (A15{1,3})
    PH(0,     0, 1, SA13(15, 65536), 10)
    PH(0,     1, 0, NOSTG, 8)
    PH(0,     2, 0, NOSTG, 8)
    PH(0,     3, 0, NOSTG, 2)
    PH(65536, 0, 1, NOSTG, 2)
    PH(65536, 1, 0, NOSTG, 0)
    PH(65536, 2, 0, NOSTG, 0)
    PH(65536, 3, 0, NOSTG, 0)

#undef PH
#undef GA
#undef GB
#undef SB01
#undef SB23
#undef SA02
#undef SA13
#undef NOSTG

    // epilogue: scatter Q*QSCALE, K, V^T (mapping verified in R16)
    #pragma unroll
    for (int m = 0; m < 8; ++m) {
        #pragma unroll
        for (int n = 0; n < 4; ++n) {
            const int col = bn + wc + n * 16 + ln_c;
            const float bcol = bias[col];
            #pragma unroll
            for (int j = 0; j < 4; ++j) {
                const int row = bm + wr + m * 16 + ln_g * 4 + j;
                float v = acc[m][n][j] + bcol;
                const int part = col >> 10;       // 0=q 1=k 2=v
                const int cc = col & 1023;
                const int h = cc >> 6, d = cc & 63;
                const int b = row >> 11, t = row & 2047;
                const int bh = b * H_ + h;
                if (part == 0)
                    Qo[((size_t)bh * T_ + t) * HD_ + d] = __float2bfloat16(v * QSCALE);
                else if (part == 1)
                    Ko[((size_t)bh * T_ + t) * HD_ + d] = __float2bfloat16(v);
                else
                    Vo[((size_t)bh * HD_ + d) * T_ + t] = __float2bfloat16(v);
            }
        }
    }
}

// ---------------------------------------------------------------- proj GEMM (R13 128^2 ring-3)
__global__ __launch_bounds__(256)
void gemm_proj(const bf16* __restrict__ A, const bf16* __restrict__ Bt,
               const float* __restrict__ bias, float* __restrict__ Fo) {
    constexpr int K = 1024;
    const int bm = blockIdx.x * 128;
    const int bn = blockIdx.y * 128;
    const int tid  = threadIdx.x;
    const int wid  = tid >> 6;
    const int lane = tid & 63;
    const int wr = (wid >> 1) * 64;
    const int wc = (wid & 1) * 64;
    const int ln_g = lane >> 4;
    const int ln_c = lane & 15;

    __shared__ bf16 sm[3][2][128][32];

    f32x4 acc[4][4] = {};

    const int g_row0 = wid * 32 + (lane >> 2);
    const int g_chk  = ((lane & 3) ^ ((lane >> 3) & 3)) * 8;
    const int l_row0 = wid * 32;
    const int colx = (ln_g * 16) ^ (((ln_c >> 1) & 3) << 4);

#define STAGE(S_, T_) {                                                               \
    gld_lds16(&A [(size_t)(bm + g_row0)      * K + (T_) * 32 + g_chk], &sm[S_][0][l_row0][0]);      \
    gld_lds16(&A [(size_t)(bm + g_row0 + 16) * K + (T_) * 32 + g_chk], &sm[S_][0][l_row0 + 16][0]); \
    gld_lds16(&Bt[(size_t)(bn + g_row0)      * K + (T_) * 32 + g_chk], &sm[S_][1][l_row0][0]);      \
    gld_lds16(&Bt[(size_t)(bn + g_row0 + 16) * K + (T_) * 32 + g_chk], &sm[S_][1][l_row0 + 16][0]); }

#define COMPUTE(S_) {                                                                    \
    bf16x8 af[4], bfr[4];                                                                \
    _Pragma("unroll")                                                                    \
    for (int m = 0; m < 4; ++m)                                                          \
        af[m] = *reinterpret_cast<const bf16x8*>(                                        \
            (const char*)&sm[S_][0][wr + m * 16 + ln_c][0] + colx);                      \
    _Pragma("unroll")                                                                    \
    for (int n = 0; n < 4; ++n)                                                          \
        bfr[n] = *reinterpret_cast<const bf16x8*>(                                       \
            (const char*)&sm[S_][1][wc + n * 16 + ln_c][0] + colx);                      \
    _Pragma("unroll")                                                                    \
    for (int m = 0; m < 4; ++m)                                                          \
        _Pragma("unroll")                                                                \
        for (int n = 0; n < 4; ++n)                                                      \
            acc[m][n] = __builtin_amdgcn_mfma_f32_16x16x32_bf16(af[m], bfr[n],           \
                                                                 acc[m][n], 0, 0, 0); }

#define WAITV4 { asm volatile("s_waitcnt vmcnt(4) lgkmcnt(0)" ::: "memory");             \
                 __builtin_amdgcn_s_barrier();                                           \
                 __builtin_amdgcn_sched_barrier(0); }
#define WAITV0 { asm volatile("s_waitcnt vmcnt(0) lgkmcnt(0)" ::: "memory");             \
                 __builtin_amdgcn_s_barrier();                                           \
                 __builtin_amdgcn_sched_barrier(0); }

    STAGE(0, 0);
    STAGE(1, 1);

    #pragma unroll 1
    for (int i = 0; i < 10; ++i) {
        const int t0 = i * 3;
        WAITV4; STAGE(2, t0 + 2); COMPUTE(0);
        WAITV4; STAGE(0, t0 + 3); COMPUTE(1);
        WAITV4; STAGE(1, t0 + 4); COMPUTE(2);
    }
    WAITV4; COMPUTE(0);
    WAITV0; COMPUTE(1);

#undef STAGE
#undef COMPUTE
#undef WAITV4
#undef WAITV0

    #pragma unroll
    for (int m = 0; m < 4; ++m) {
        #pragma unroll
        for (int n = 0; n < 4; ++n) {
            const int col = bn + wc + n * 16 + ln_c;
            const float bcol = bias[col];
            #pragma unroll
            for (int j = 0; j < 4; ++j) {
                const int row = bm + wr + m * 16 + ln_g * 4 + j;
                Fo[(size_t)row * D_ + col] = acc[m][n][j] + bcol;
            }
        }
    }
}

// ---------------------------------------------------------------- causal flash attention v4b (frozen)
__global__ __launch_bounds__(256, 4)
void attn_kernel(const bf16* __restrict__ Q, const bf16* __restrict__ K,
                 const bf16* __restrict__ Vt, bf16* __restrict__ ctx) {
    const int bh = blockIdx.x & 63;
    const int qt = 31 - (blockIdx.x >> 6);
    const int tid  = threadIdx.x;
    const int wave = tid >> 6;
    const int lane = tid & 63;
    const int ln_g = lane >> 4;
    const int ln_c = lane & 15;

    const bf16* Qp = Q  + (size_t)bh * T_ * HD_;
    const bf16* Kp = K  + (size_t)bh * T_ * HD_;
    const bf16* Vp = Vt + (size_t)bh * HD_ * T_;

    __shared__ bf16 Ks[64][72];
    __shared__ bf16 Vs[64][72];

    const int srow = tid >> 3;
    const int sc8  = (tid & 7) * 8;

    const int b = bh >> 4, h = bh & 15;

    const int qbase = qt * 64;
    const int qglob = qbase + wave * 16 + ln_c;

    const bf16x8 qf0 = *reinterpret_cast<const bf16x8*>(&Qp[(size_t)qglob * HD_ + ln_g * 8]);
    const bf16x8 qf1 = *reinterpret_cast<const bf16x8*>(&Qp[(size_t)qglob * HD_ + 32 + ln_g * 8]);

    f32x4 o[4] = {};
    float m = -INFINITY, l = 0.f;

    const int nk = qt + 1;

    int4 kr0, kr1, vr0, vr1;
    kr0 = *reinterpret_cast<const int4*>(&Kp[(size_t)srow * HD_ + sc8]);
    kr1 = *reinterpret_cast<const int4*>(&Kp[(size_t)(srow + 32) * HD_ + sc8]);
    vr0 = *reinterpret_cast<const int4*>(&Vp[(size_t)srow * T_ + sc8]);
    vr1 = *reinterpret_cast<const int4*>(&Vp[(size_t)(srow + 32) * T_ + sc8]);
    *reinterpret_cast<int4*>(&Ks[srow][sc8])      = kr0;
    *reinterpret_cast<int4*>(&Ks[srow + 32][sc8]) = kr1;
    *reinterpret_cast<int4*>(&Vs[srow][sc8])      = vr0;
    *reinterpret_cast<int4*>(&Vs[srow + 32][sc8]) = vr1;
    __syncthreads();

    for (int it = 0; it < nk; ++it) {
        const int kb = it * 64;
        const bool notlast = (it + 1 < nk);
        if (notlast) {
            const int kn = kb + 64;
            kr0 = *reinterpret_cast<const int4*>(&Kp[(size_t)(kn + srow) * HD_ + sc8]);
            kr1 = *reinterpret_cast<const int4*>(&Kp[(size_t)(kn + srow + 32) * HD_ + sc8]);
            vr0 = *reinterpret_cast<const int4*>(&Vp[(size_t)srow * T_ + kn + sc8]);
            vr1 = *reinterpret_cast<const int4*>(&Vp[(size_t)(srow + 32) * T_ + kn + sc8]);
        }

        f32x4 st[4];
        __builtin_amdgcn_s_setprio(1);
        #pragma unroll
        for (int kk = 0; kk < 4; ++kk) {
            bf16x8 kfa = *reinterpret_cast<const bf16x8*>(&Ks[kk * 16 + ln_c][ln_g * 8]);
            bf16x8 kfb = *reinterpret_cast<const bf16x8*>(&Ks[kk * 16 + ln_c][32 + ln_g * 8]);
            f32x4 z = {0.f, 0.f, 0.f, 0.f};
            z = __builtin_amdgcn_mfma_f32_16x16x32_bf16(kfa, qf0, z, 0, 0, 0);
            z = __builtin_amdgcn_mfma_f32_16x16x32_bf16(kfb, qf1, z, 0, 0, 0);
            st[kk] = z;
        }
        __builtin_amdgcn_s_setprio(0);

        if (!notlast) {
            #pragma unroll
            for (int kk = 0; kk < 4; ++kk)
                #pragma unroll
                for (int j = 0; j < 4; ++j)
                    if (kb + kk * 16 + ln_g * 4 + j > qglob) st[kk][j] = -INFINITY;
        }

        float mx = -INFINITY;
        #pragma unroll
        for (int kk = 0; kk < 4; ++kk)
            #pragma unroll
            for (int j = 0; j < 4; ++j)
                mx = fmaxf(mx, st[kk][j]);
        if (!__all(mx - m <= 8.f)) {
            float r = fmaxf(mx, __shfl_xor(mx, 16));
            r = fmaxf(r, __shfl_xor(r, 32));
            const float mnew = fmaxf(m, r);
            const float alpha = exp2f(m - mnew);
            l *= alpha;
            #pragma unroll
            for (int dt = 0; dt < 4; ++dt)
                #pragma unroll
                for (int j = 0; j < 4; ++j)
                    o[dt][j] *= alpha;
            m = mnew;
        }

        #pragma unroll
        for (int kk = 0; kk < 4; ++kk) {
            float p0 = exp2f(st[kk][0] - m);
            float p1 = exp2f(st[kk][1] - m);
            float p2 = exp2f(st[kk][2] - m);
            float p3 = exp2f(st[kk][3] - m);
            l += (p0 + p1) + (p2 + p3);
            uint2 pw;
            pw.x = bfbits(p0) | (bfbits(p1) << 16);
            pw.y = bfbits(p2) | (bfbits(p3) << 16);
            const s16x4 ps = __builtin_bit_cast(s16x4, pw);
            __builtin_amdgcn_s_setprio(1);
            #pragma unroll
            for (int dt = 0; dt < 4; ++dt) {
                s16x4 vf = *reinterpret_cast<const s16x4*>(
                    &Vs[dt * 16 + ln_c][kk * 16 + ln_g * 4]);
                o[dt] = mfma16(vf, ps, o[dt]);
            }
            __builtin_amdgcn_s_setprio(0);
        }

        if (notlast) {
            __syncthreads();
            *reinterpret_cast<int4*>(&Ks[srow][sc8])      = kr0;
            *reinterpret_cast<int4*>(&Ks[srow + 32][sc8]) = kr1;
            *reinterpret_cast<int4*>(&Vs[srow][sc8])      = vr0;
            *reinterpret_cast<int4*>(&Vs[srow + 32][sc8]) = vr1;
            __syncthreads();
        }
    }

    l += __shfl_xor(l, 16);
    l += __shfl_xor(l, 32);
    const float inv = 1.0f / l;
    bf16* dst = ctx + ((size_t)(b * T_ + qglob)) * D_ + h * HD_;
    #pragma unroll
    for (int dt = 0; dt < 4; ++dt) {
        union { bf16 hh[4]; uint2 u; } ok;
        #pragma unroll
        for (int j = 0; j < 4; ++j)
            ok.hh[j] = __float2bfloat16(o[dt][j] * inv);
        *reinterpret_cast<uint2*>(&dst[dt * 16 + ln_g * 4]) = ok.u;
    }
}

// ---------------------------------------------------------------- launch
extern "C" void kernel_launch(void* const* d_in, const int* in_sizes, int n_in,
                              void* d_out, int out_size, void* d_ws, size_t ws_size,
                              hipStream_t stream) {
    const float* x      = (const float*)d_in[0];
    const float* W_attn = (const float*)d_in[1];
    const float* b_attn = (const float*)d_in[2];
    const float* W_proj = (const float*)d_in[3];
    const float* b_proj = (const float*)d_in[4];
    float* out = (float*)d_out;

    char* ws = (char*)d_ws;
    bf16* xh  = (bf16*)ws;  ws += (size_t)BT_ * D_ * 2;
    bf16* WaT = (bf16*)ws;  ws += (size_t)3 * D_ * D_ * 2;
    bf16* WpT = (bf16*)ws;  ws += (size_t)D_ * D_ * 2;
    bf16* Qb  = (bf16*)ws;  ws += (size_t)BH_ * T_ * HD_ * 2;
    bf16* Kb  = (bf16*)ws;  ws += (size_t)BH_ * T_ * HD_ * 2;
    bf16* Vb  = (bf16*)ws;  ws += (size_t)BH_ * T_ * HD_ * 2;
    bf16* ctx = (bf16*)ws;  ws += (size_t)BT_ * D_ * 2;

    prep_kernel<<<8192, 256, 0, stream>>>(x, W_attn, W_proj, xh, WaT, WpT);

    // QKV: 256^2 8-phase, grid x=n(12), y=m(32), 128KB dynamic LDS
    gemm_qkv8p<<<dim3(12, 32), 512, 131072, stream>>>(xh, WaT, b_attn, Qb, Kb, Vb);

    attn_kernel<<<dim3(BH_ * 32), 256, 0, stream>>>(Qb, Kb, Vb, ctx);

    gemm_proj<<<dim3(64, 8), 256, 0, stream>>>(ctx, WpT, b_proj, out);
}

// Round 19
// 176.221 us; speedup vs baseline: 1.0753x; 1.0753x over previous
//
#include <hip/hip_runtime.h>
#include <hip/hip_bf16.h>

using bf16 = __hip_bfloat16;
typedef __attribute__((ext_vector_type(8))) __bf16 bf16x8;
typedef __attribute__((ext_vector_type(4))) short s16x4;
typedef __attribute__((ext_vector_type(4))) float f32x4;

#define B_   4
#define T_   2048
#define D_   1024
#define H_   16
#define HD_  64
#define BH_  (B_ * H_)
#define BT_  (B_ * T_)

// Q pre-scale: 1/sqrt(64) * log2(e)  -> softmax computed with exp2
#define QSCALE 0.18033688011112042f

__device__ __forceinline__ void gld_lds16(const void* g, void* l) {
    __builtin_amdgcn_global_load_lds(
        (const __attribute__((address_space(1))) unsigned int*)g,
        (__attribute__((address_space(3))) unsigned int*)l,
        16, 0, 0);
}

__device__ __forceinline__ f32x4 mfma16(s16x4 a, s16x4 b, f32x4 c) {
#if defined(__HIP_DEVICE_COMPILE__)
  #if __has_builtin(__builtin_amdgcn_mfma_f32_16x16x16bf16_1k)
    return __builtin_amdgcn_mfma_f32_16x16x16bf16_1k(a, b, c, 0, 0, 0);
  #else
    f32x4 d;
    asm volatile("v_mfma_f32_16x16x16_bf16 %0, %1, %2, %3\n\ts_nop 7\n\ts_nop 7"
                 : "=v"(d) : "v"(a), "v"(b), "v"(c));
    return d;
  #endif
#else
    (void)a; (void)b;
    return c;
#endif
}

__device__ __forceinline__ unsigned bfbits(float x) {
    return (unsigned)__builtin_bit_cast(unsigned short, __float2bfloat16(x));
}

// ---------------------------------------------------------------- fused prep (R17, frozen)
__global__ __launch_bounds__(256)
void prep_kernel(const float* __restrict__ x,
                 const float* __restrict__ W_attn,
                 const float* __restrict__ W_proj,
                 bf16* __restrict__ xh, bf16* __restrict__ WaT, bf16* __restrict__ WpT) {
    __shared__ float tile[32][33];
    const int blk = blockIdx.x;
    const int tid = threadIdx.x;

    if (blk < 4096) {
        const size_t i = ((size_t)blk * 256 + tid) * 8;
        float4 v0 = *reinterpret_cast<const float4*>(x + i);
        float4 v1 = *reinterpret_cast<const float4*>(x + i + 4);
        uint4 p;
        p.x = bfbits(v0.x) | (bfbits(v0.y) << 16);
        p.y = bfbits(v0.z) | (bfbits(v0.w) << 16);
        p.z = bfbits(v1.x) | (bfbits(v1.y) << 16);
        p.w = bfbits(v1.z) | (bfbits(v1.w) << 16);
        *reinterpret_cast<uint4*>(xh + i) = p;
        return;
    }

    if (blk < 4096 + 3072) {
        const int t = blk - 4096;
        const int nb = (t % 96) * 32, kb = (t / 96) * 32;
        const int tx = tid & 31, ty = tid >> 5;
        #pragma unroll
        for (int i = 0; i < 32; i += 8)
            tile[ty + i][tx] = W_attn[(size_t)(kb + ty + i) * 3072 + nb + tx];
        __syncthreads();
        #pragma unroll
        for (int i = 0; i < 32; i += 8)
            WaT[(size_t)(nb + ty + i) * 1024 + kb + tx] = __float2bfloat16(tile[tx][ty + i]);
    } else {
        const int t = blk - 4096 - 3072;
        const int nb = (t % 32) * 32, kb = (t / 32) * 32;
        const int tx = tid & 31, ty = tid >> 5;
        #pragma unroll
        for (int i = 0; i < 32; i += 8)
            tile[ty + i][tx] = W_proj[(size_t)(kb + ty + i) * 1024 + nb + tx];
        __syncthreads();
        #pragma unroll
        for (int i = 0; i < 32; i += 8)
            WpT[(size_t)(nb + ty + i) * 1024 + kb + tx] = __float2bfloat16(tile[tx][ty + i]);
    }
}

// ---------------------------------------------------------------- GEMM  C = A @ Bt^T (+bias)
// 128x128 tile, K=1024, BK=32, ring-3 LDS (48 KB), counted vmcnt — R13-verified
// schedule, now with 8 WAVES (512 thr): per-wave 32x64 C (acc[2][4]), 4Mx2N wave
// grid -> 24 waves/CU = 6/SIMD (double chain-hiding vs R13's 3/SIMD). Stage = 2 DMA
// calls (8 waves x 1KB); counted waits vmcnt(2)/vmcnt(0), same ledger induction.
// XOR swizzle identical (16-row-aligned bases -> same per-lane math; 0-conflict).
// MODE 0: QKV scatter. MODE 1: fp32 + bias.
template <int MODE>
__global__ __launch_bounds__(512)
void gemm_bt(const bf16* __restrict__ A, const bf16* __restrict__ Bt,
             const float* __restrict__ bias,
             bf16* __restrict__ Qo, bf16* __restrict__ Ko, bf16* __restrict__ Vo,
             float* __restrict__ Fo) {
    constexpr int K = 1024;
    const int bm = blockIdx.x * 128;
    const int bn = blockIdx.y * 128;
    const int tid  = threadIdx.x;
    const int wid  = tid >> 6;          // 0..7
    const int lane = tid & 63;
    const int wr = (wid >> 1) * 32;     // 4 M-rows of 32
    const int wc = (wid & 1) * 64;      // 2 N-cols of 64
    const int ln_g = lane >> 4;         // 0..3
    const int ln_c = lane & 15;         // 0..15

    __shared__ bf16 sm[3][2][128][32];  // ring-3: [slot][A/B][row][col]

    f32x4 acc[2][4] = {};

    // staging: one call covers 128 rows (8 waves x 16 rows, 4 lanes/row)
    const int g_row0 = wid * 16 + (lane >> 2);               // 0..127
    const int g_chk  = ((lane & 3) ^ ((lane >> 3) & 3)) * 8; // pre-swizzled elem off
    const int l_row0 = wid * 16;                             // wave-uniform LDS row base
    const int colx = (ln_g * 16) ^ (((ln_c >> 1) & 3) << 4); // read-side swizzle

#define STAGE(S_, T_) {                                                               \
    gld_lds16(&A [(size_t)(bm + g_row0) * K + (T_) * 32 + g_chk], &sm[S_][0][l_row0][0]); \
    gld_lds16(&Bt[(size_t)(bn + g_row0) * K + (T_) * 32 + g_chk], &sm[S_][1][l_row0][0]); }

#define COMPUTE(S_) {                                                                    \
    bf16x8 af[2], bfr[4];                                                                \
    _Pragma("unroll")                                                                    \
    for (int m = 0; m < 2; ++m)                                                          \
        af[m] = *reinterpret_cast<const bf16x8*>(                                        \
            (const char*)&sm[S_][0][wr + m * 16 + ln_c][0] + colx);                      \
    _Pragma("unroll")                                                                    \
    for (int n = 0; n < 4; ++n)                                                          \
        bfr[n] = *reinterpret_cast<const bf16x8*>(                                       \
            (const char*)&sm[S_][1][wc + n * 16 + ln_c][0] + colx);                      \
    _Pragma("unroll")                                                                    \
    for (int m = 0; m < 2; ++m)                                                          \
        _Pragma("unroll")                                                                \
        for (int n = 0; n < 4; ++n)                                                      \
            acc[m][n] = __builtin_amdgcn_mfma_f32_16x16x32_bf16(af[m], bfr[n],           \
                                                                 acc[m][n], 0, 0, 0); }

#define WAITV2 { asm volatile("s_waitcnt vmcnt(2) lgkmcnt(0)" ::: "memory");             \
                 __builtin_amdgcn_s_barrier();                                           \
                 __builtin_amdgcn_sched_barrier(0); }
#define WAITV0 { asm volatile("s_waitcnt vmcnt(0) lgkmcnt(0)" ::: "memory");             \
                 __builtin_amdgcn_s_barrier();                                           \
                 __builtin_amdgcn_sched_barrier(0); }

    STAGE(0, 0);
    STAGE(1, 1);

    // 30 tiles in 10 triples; per triple i: stage tiles 3i+2,3i+3,3i+4 (slot t%3),
    // compute tiles 3i,3i+1,3i+2.  (R13 induction; 2 calls/stage -> vmcnt(2).)
    #pragma unroll 1
    for (int i = 0; i < 10; ++i) {
        const int t0 = i * 3;
        WAITV2; STAGE(2, t0 + 2); COMPUTE(0);
        WAITV2; STAGE(0, t0 + 3); COMPUTE(1);
        WAITV2; STAGE(1, t0 + 4); COMPUTE(2);
    }
    WAITV2; COMPUTE(0);   // tile 30 (tile 31's stage in flight)
    WAITV0; COMPUTE(1);   // tile 31

#undef STAGE
#undef COMPUTE
#undef WAITV2
#undef WAITV0

    #pragma unroll
    for (int m = 0; m < 2; ++m) {
        #pragma unroll
        for (int n = 0; n < 4; ++n) {
            const int col = bn + wc + n * 16 + ln_c;
            const float bcol = bias[col];
            #pragma unroll
            for (int j = 0; j < 4; ++j) {
                const int row = bm + wr + m * 16 + ln_g * 4 + j;
                float v = acc[m][n][j] + bcol;
                if (MODE == 0) {
                    const int part = col >> 10;       // 0=q 1=k 2=v
                    const int cc = col & 1023;
                    const int h = cc >> 6, d = cc & 63;
                    const int b = row >> 11, t = row & 2047;
                    const int bh = b * H_ + h;
                    if (part == 0)
                        Qo[((size_t)bh * T_ + t) * HD_ + d] = __float2bfloat16(v * QSCALE);
                    else if (part == 1)
                        Ko[((size_t)bh * T_ + t) * HD_ + d] = __float2bfloat16(v);
                    else
                        Vo[((size_t)bh * HD_ + d) * T_ + t] = __float2bfloat16(v);
                } else {
                    Fo[(size_t)row * D_ + col] = v;
                }
            }
        }
    }
}

// ---------------------------------------------------------------- causal flash attention v4b (frozen)
__global__ __launch_bounds__(256, 4)
void attn_kernel(const bf16* __restrict__ Q, const bf16* __restrict__ K,
                 const bf16* __restrict__ Vt, bf16* __restrict__ ctx) {
    const int bh = blockIdx.x & 63;
    const int qt = 31 - (blockIdx.x >> 6);
    const int tid  = threadIdx.x;
    const int wave = tid >> 6;
    const int lane = tid & 63;
    const int ln_g = lane >> 4;
    const int ln_c = lane & 15;

    const bf16* Qp = Q  + (size_t)bh * T_ * HD_;
    const bf16* Kp = K  + (size_t)bh * T_ * HD_;
    const bf16* Vp = Vt + (size_t)bh * HD_ * T_;

    __shared__ bf16 Ks[64][72];
    __shared__ bf16 Vs[64][72];

    const int srow = tid >> 3;
    const int sc8  = (tid & 7) * 8;

    const int b = bh >> 4, h = bh & 15;

    const int qbase = qt * 64;
    const int qglob = qbase + wave * 16 + ln_c;

    const bf16x8 qf0 = *reinterpret_cast<const bf16x8*>(&Qp[(size_t)qglob * HD_ + ln_g * 8]);
    const bf16x8 qf1 = *reinterpret_cast<const bf16x8*>(&Qp[(size_t)qglob * HD_ + 32 + ln_g * 8]);

    f32x4 o[4] = {};
    float m = -INFINITY, l = 0.f;

    const int nk = qt + 1;

    int4 kr0, kr1, vr0, vr1;
    kr0 = *reinterpret_cast<const int4*>(&Kp[(size_t)srow * HD_ + sc8]);
    kr1 = *reinterpret_cast<const int4*>(&Kp[(size_t)(srow + 32) * HD_ + sc8]);
    vr0 = *reinterpret_cast<const int4*>(&Vp[(size_t)srow * T_ + sc8]);
    vr1 = *reinterpret_cast<const int4*>(&Vp[(size_t)(srow + 32) * T_ + sc8]);
    *reinterpret_cast<int4*>(&Ks[srow][sc8])      = kr0;
    *reinterpret_cast<int4*>(&Ks[srow + 32][sc8]) = kr1;
    *reinterpret_cast<int4*>(&Vs[srow][sc8])      = vr0;
    *reinterpret_cast<int4*>(&Vs[srow + 32][sc8]) = vr1;
    __syncthreads();

    for (int it = 0; it < nk; ++it) {
        const int kb = it * 64;
        const bool notlast = (it + 1 < nk);
        if (notlast) {
            const int kn = kb + 64;
            kr0 = *reinterpret_cast<const int4*>(&Kp[(size_t)(kn + srow) * HD_ + sc8]);
            kr1 = *reinterpret_cast<const int4*>(&Kp[(size_t)(kn + srow + 32) * HD_ + sc8]);
            vr0 = *reinterpret_cast<const int4*>(&Vp[(size_t)srow * T_ + kn + sc8]);
            vr1 = *reinterpret_cast<const int4*>(&Vp[(size_t)(srow + 32) * T_ + kn + sc8]);
        }

        f32x4 st[4];
        __builtin_amdgcn_s_setprio(1);
        #pragma unroll
        for (int kk = 0; kk < 4; ++kk) {
            bf16x8 kfa = *reinterpret_cast<const bf16x8*>(&Ks[kk * 16 + ln_c][ln_g * 8]);
            bf16x8 kfb = *reinterpret_cast<const bf16x8*>(&Ks[kk * 16 + ln_c][32 + ln_g * 8]);
            f32x4 z = {0.f, 0.f, 0.f, 0.f};
            z = __builtin_amdgcn_mfma_f32_16x16x32_bf16(kfa, qf0, z, 0, 0, 0);
            z = __builtin_amdgcn_mfma_f32_16x16x32_bf16(kfb, qf1, z, 0, 0, 0);
            st[kk] = z;
        }
        __builtin_amdgcn_s_setprio(0);

        if (!notlast) {
            #pragma unroll
            for (int kk = 0; kk < 4; ++kk)
                #pragma unroll
                for (int j = 0; j < 4; ++j)
                    if (kb + kk * 16 + ln_g * 4 + j > qglob) st[kk][j] = -INFINITY;
        }

        float mx = -INFINITY;
        #pragma unroll
        for (int kk = 0; kk < 4; ++kk)
            #pragma unroll
            for (int j = 0; j < 4; ++j)
                mx = fmaxf(mx, st[kk][j]);
        if (!__all(mx - m <= 8.f)) {
            float r = fmaxf(mx, __shfl_xor(mx, 16));
            r = fmaxf(r, __shfl_xor(r, 32));
            const float mnew = fmaxf(m, r);
            const float alpha = exp2f(m - mnew);
            l *= alpha;
            #pragma unroll
            for (int dt = 0; dt < 4; ++dt)
                #pragma unroll
                for (int j = 0; j < 4; ++j)
                    o[dt][j] *= alpha;
            m = mnew;
        }

        #pragma unroll
        for (int kk = 0; kk < 4; ++kk) {
            float p0 = exp2f(st[kk][0] - m);
            float p1 = exp2f(st[kk][1] - m);
            float p2 = exp2f(st[kk][2] - m);
            float p3 = exp2f(st[kk][3] - m);
            l += (p0 + p1) + (p2 + p3);
            uint2 pw;
            pw.x = bfbits(p0) | (bfbits(p1) << 16);
            pw.y = bfbits(p2) | (bfbits(p3) << 16);
            const s16x4 ps = __builtin_bit_cast(s16x4, pw);
            __builtin_amdgcn_s_setprio(1);
            #pragma unroll
            for (int dt = 0; dt < 4; ++dt) {
                s16x4 vf = *reinterpret_cast<const s16x4*>(
                    &Vs[dt * 16 + ln_c][kk * 16 + ln_g * 4]);
                o[dt] = mfma16(vf, ps, o[dt]);
            }
            __builtin_amdgcn_s_setprio(0);
        }

        if (notlast) {
            __syncthreads();
            *reinterpret_cast<int4*>(&Ks[srow][sc8])      = kr0;
            *reinterpret_cast<int4*>(&Ks[srow + 32][sc8]) = kr1;
            *reinterpret_cast<int4*>(&Vs[srow][sc8])      = vr0;
            *reinterpret_cast<int4*>(&Vs[srow + 32][sc8]) = vr1;
            __syncthreads();
        }
    }

    l += __shfl_xor(l, 16);
    l += __shfl_xor(l, 32);
    const float inv = 1.0f / l;
    bf16* dst = ctx + ((size_t)(b * T_ + qglob)) * D_ + h * HD_;
    #pragma unroll
    for (int dt = 0; dt < 4; ++dt) {
        union { bf16 hh[4]; uint2 u; } ok;
        #pragma unroll
        for (int j = 0; j < 4; ++j)
            ok.hh[j] = __float2bfloat16(o[dt][j] * inv);
        *reinterpret_cast<uint2*>(&dst[dt * 16 + ln_g * 4]) = ok.u;
    }
}

// ---------------------------------------------------------------- launch
extern "C" void kernel_launch(void* const* d_in, const int* in_sizes, int n_in,
                              void* d_out, int out_size, void* d_ws, size_t ws_size,
                              hipStream_t stream) {
    const float* x      = (const float*)d_in[0];
    const float* W_attn = (const float*)d_in[1];
    const float* b_attn = (const float*)d_in[2];
    const float* W_proj = (const float*)d_in[3];
    const float* b_proj = (const float*)d_in[4];
    float* out = (float*)d_out;

    char* ws = (char*)d_ws;
    bf16* xh  = (bf16*)ws;  ws += (size_t)BT_ * D_ * 2;
    bf16* WaT = (bf16*)ws;  ws += (size_t)3 * D_ * D_ * 2;
    bf16* WpT = (bf16*)ws;  ws += (size_t)D_ * D_ * 2;
    bf16* Qb  = (bf16*)ws;  ws += (size_t)BH_ * T_ * HD_ * 2;
    bf16* Kb  = (bf16*)ws;  ws += (size_t)BH_ * T_ * HD_ * 2;
    bf16* Vb  = (bf16*)ws;  ws += (size_t)BH_ * T_ * HD_ * 2;
    bf16* ctx = (bf16*)ws;  ws += (size_t)BT_ * D_ * 2;

    prep_kernel<<<8192, 256, 0, stream>>>(x, W_attn, W_proj, xh, WaT, WpT);

    gemm_bt<0><<<dim3(BT_ / 128, 3 * D_ / 128), 512, 0, stream>>>(
        xh, WaT, b_attn, Qb, Kb, Vb, nullptr);

    attn_kernel<<<dim3(BH_ * 32), 256, 0, stream>>>(Qb, Kb, Vb, ctx);

    gemm_bt<1><<<dim3(BT_ / 128, D_ / 128), 512, 0, stream>>>(
        ctx, WpT, b_proj, nullptr, nullptr, nullptr, out);
}